// Round 2
// baseline (776.387 us; speedup 1.0000x reference)
//
#include <hip/hip_runtime.h>
#include <math.h>
#include <stdint.h>

typedef _Float16 f16;
typedef _Float16 f16x8 __attribute__((ext_vector_type(8)));
typedef float f32x16 __attribute__((ext_vector_type(16)));

// ws layout (bytes): f16 weights transposed+padded, f32 biases.
//   uW1t: f16[128][72]  (W1^T [n][k], k<64)    18432
//   uW2t: f16[64][136]  (W2^T [n][k], k<128)   17408
//   iW1t / iW2t same                           18432 / 17408
//   bias: f32[384] = ub1[128] ub2[64] ib1[128] ib2[64]
#define WS_UW1T 0
#define WS_UW2T 18432
#define WS_IW1T 35840
#define WS_IW2T 54272
#define WS_BIAS 71680

__global__ __launch_bounds__(256) void prep_kernel(
    const float* __restrict__ uW1, const float* __restrict__ ub1,
    const float* __restrict__ uW2, const float* __restrict__ ub2,
    const float* __restrict__ iW1, const float* __restrict__ ib1,
    const float* __restrict__ iW2, const float* __restrict__ ib2,
    char* __restrict__ ws)
{
  int g = blockIdx.x * 256 + threadIdx.x;
  if (g < 8192) {                       // uW1 [64][128] row-major -> [n][k]
    int n = g >> 6, k = g & 63;
    ((f16*)(ws + WS_UW1T))[n * 72 + k] = (f16)uW1[k * 128 + n];
  } else if (g < 16384) {               // uW2 [128][64] -> [n][k]
    int j = g - 8192; int n = j >> 7, k = j & 127;
    ((f16*)(ws + WS_UW2T))[n * 136 + k] = (f16)uW2[k * 64 + n];
  } else if (g < 24576) {
    int j = g - 16384; int n = j >> 6, k = j & 63;
    ((f16*)(ws + WS_IW1T))[n * 72 + k] = (f16)iW1[k * 128 + n];
  } else if (g < 32768) {
    int j = g - 24576; int n = j >> 7, k = j & 127;
    ((f16*)(ws + WS_IW2T))[n * 136 + k] = (f16)iW2[k * 64 + n];
  } else if (g < 33152) {
    int j = g - 32768;
    float v = (j < 128) ? ub1[j]
            : (j < 192) ? ub2[j - 128]
            : (j < 320) ? ib1[j - 192]
                        : ib2[j - 320];
    ((float*)(ws + WS_BIAS))[j] = v;
  }
}

__device__ inline f32x16 zero16() {
  f32x16 z;
#pragma unroll
  for (int i = 0; i < 16; ++i) z[i] = 0.f;
  return z;
}

__device__ inline f16x8 pack8(float4 a, float4 b) {
  f16x8 p;
  p[0] = (f16)a.x; p[1] = (f16)a.y; p[2] = (f16)a.z; p[3] = (f16)a.w;
  p[4] = (f16)b.x; p[5] = (f16)b.y; p[6] = (f16)b.z; p[7] = (f16)b.w;
  return p;
}

// One tower over 64 rows. Entry (post-barrier): sX = X f16[64][72].
// Weights/bias read directly from global (L1/L2-hot ws). One internal
// barrier between L1-epilogue(H->LDS) and L2. Exit: u = relu(H@W2+b2)
// in C-frag layout (wave's 32x32 subtile: mt=wave>>1, nt=wave&1).
// NO trailing barrier.
__device__ inline void tower(
    const f16* __restrict__ sX, f16* __restrict__ sH,
    const f16* __restrict__ gW1t, const f16* __restrict__ gW2t,
    const float* __restrict__ gB1, const float* __restrict__ gB2,
    int wave, int l31, int lhi, f32x16& u)
{
  // ---- L1: [64,64] @ [64,128]: 2Mt x 4Nt; wave -> mt=w>>1, nt={ntb,ntb+1}
  const int mt = wave >> 1, ntb = (wave & 1) * 2;
  f32x16 h0 = zero16(), h1 = zero16();
#pragma unroll
  for (int ks = 0; ks < 4; ++ks) {
    int ko = ks * 16 + lhi * 8;
    f16x8 a  = *(const f16x8*)(sX + (mt * 32 + l31) * 72 + ko);
    f16x8 b0 = *(const f16x8*)(gW1t + (ntb * 32 + l31) * 72 + ko);
    f16x8 b1 = *(const f16x8*)(gW1t + (ntb * 32 + 32 + l31) * 72 + ko);
    h0 = __builtin_amdgcn_mfma_f32_32x32x16_f16(a, b0, h0, 0, 0, 0);
    h1 = __builtin_amdgcn_mfma_f32_32x32x16_f16(a, b1, h1, 0, 0, 0);
  }
  {
    float bias0 = gB1[ntb * 32 + l31];
    float bias1 = gB1[ntb * 32 + 32 + l31];
    int col0 = ntb * 32 + l31, col1 = col0 + 32;
#pragma unroll
    for (int r = 0; r < 16; ++r) {
      int row = mt * 32 + (r & 3) + 8 * (r >> 2) + 4 * lhi;   // C/D row map
      sH[row * 136 + col0] = (f16)fmaxf(h0[r] + bias0, 0.f);
      sH[row * 136 + col1] = (f16)fmaxf(h1[r] + bias1, 0.f);
    }
  }
  __syncthreads();   // H complete; also fences this tower's sX reads

  // ---- L2: [64,128] @ [128,64]: 2Mt x 2Nt; wave -> mt=w>>1, nt=w&1
  const int nt = wave & 1;
  f32x16 v = zero16();
#pragma unroll
  for (int ks = 0; ks < 8; ++ks) {
    int ko = ks * 16 + lhi * 8;
    f16x8 a = *(const f16x8*)(sH + (mt * 32 + l31) * 136 + ko);
    f16x8 b = *(const f16x8*)(gW2t + (nt * 32 + l31) * 136 + ko);
    v = __builtin_amdgcn_mfma_f32_32x32x16_f16(a, b, v, 0, 0, 0);
  }
  float b2 = gB2[nt * 32 + l31];
#pragma unroll
  for (int r = 0; r < 16; ++r) u[r] = fmaxf(v[r] + b2, 0.f);
}

__global__ __launch_bounds__(256, 4) void TwoTowerModel_71708773974789_kernel(
    const int* __restrict__ user_ids, const int* __restrict__ item_ids,
    const float* __restrict__ user_table, const float* __restrict__ item_table,
    const char* __restrict__ ws, float* __restrict__ out)
{
  // 35840 B LDS -> 4 blocks/CU (LDS); VGPR target <=128 for 4 waves/SIMD
  __shared__ __attribute__((aligned(16))) char smem[35840];
  f16* sX = (f16*)smem;                 // X f16[64][72]; later U spill
  f16* sH = (f16*)(smem + 9216);        // H f16[64][136]
  f16* sI = (f16*)(smem + 26624);       // I spill f16[64][72]

  const f16*   gUW1 = (const f16*)(ws + WS_UW1T);
  const f16*   gUW2 = (const f16*)(ws + WS_UW2T);
  const f16*   gIW1 = (const f16*)(ws + WS_IW1T);
  const f16*   gIW2 = (const f16*)(ws + WS_IW2T);
  const float* gB   = (const float*)(ws + WS_BIAS);

  const int tid = threadIdx.x;
  const int wave = tid >> 6, lane = tid & 63, l31 = lane & 31, lhi = lane >> 5;
  const int rbase = blockIdx.x * 64;
  const int row = tid >> 2, q = tid & 3;     // 4 threads/row, 64B each

  // ---- issue both gathers up front; item data parks in VGPRs through
  // the whole user tower (latency hidden under compute).
  const int uid = user_ids[rbase + row];
  const int iid = item_ids[rbase + row];
  const float4* usrc = (const float4*)(user_table + (size_t)uid * 64 + q * 16);
  const float4* isrc = (const float4*)(item_table + (size_t)iid * 64 + q * 16);
  float4 ua = usrc[0], ub = usrc[1], uc = usrc[2], ud = usrc[3];
  float4 pa = isrc[0], pb = isrc[1], pc = isrc[2], pd = isrc[3];

  {
    f16x8* dst = (f16x8*)(sX + row * 72 + q * 16);
    dst[0] = pack8(ua, ub);
    dst[1] = pack8(uc, ud);
  }
  __syncthreads();                                   // B1: user X staged

  f32x16 u, iacc;
  tower(sX, sH, gUW1, gUW2, gB + 0, gB + 128, wave, l31, lhi, u);
  // post-B2: all user L1 sX reads done -> overwrite with item X (regs, no wait)
  {
    f16x8* dst = (f16x8*)(sX + row * 72 + q * 16);
    dst[0] = pack8(pa, pb);
    dst[1] = pack8(pc, pd);
  }
  __syncthreads();                                   // B3: item X + sH free

  tower(sX, sH, gIW1, gIW2, gB + 192, gB + 320, wave, l31, lhi, iacc);
  // post-B4 (inside tower): item L1 sX reads done -> spill u over sX.
  // L2i only reads sH; sI is private-use. No barrier needed before writes.
  {
    const int mt = wave >> 1, nt = wave & 1;
#pragma unroll
    for (int r = 0; r < 16; ++r) {
      int rr = mt * 32 + (r & 3) + 8 * (r >> 2) + 4 * lhi;
      sX[rr * 72 + nt * 32 + l31] = (f16)u[r];
      sI[rr * 72 + nt * 32 + l31] = (f16)iacc[r];
    }
  }
  __syncthreads();                                   // B5: u,i visible

  // ---- dot + norms: 4 threads/row, 16 elems each, shfl-reduce over q
  {
    const f16x8* up = (const f16x8*)(sX + row * 72 + q * 16);
    const f16x8* ip = (const f16x8*)(sI + row * 72 + q * 16);
    f16x8 u0 = up[0], u1 = up[1], i0 = ip[0], i1 = ip[1];
    float sui = 0.f, suu = 0.f, sii = 0.f;
#pragma unroll
    for (int e = 0; e < 8; ++e) {
      float a0 = (float)u0[e], b0 = (float)i0[e];
      float a1 = (float)u1[e], b1 = (float)i1[e];
      sui += a0 * b0 + a1 * b1;
      suu += a0 * a0 + a1 * a1;
      sii += b0 * b0 + b1 * b1;
    }
    sui += __shfl_xor(sui, 1); suu += __shfl_xor(suu, 1); sii += __shfl_xor(sii, 1);
    sui += __shfl_xor(sui, 2); suu += __shfl_xor(suu, 2); sii += __shfl_xor(sii, 2);
    if (q == 0) {
      float nu = fmaxf(sqrtf(suu), 1e-12f);
      float nv = fmaxf(sqrtf(sii), 1e-12f);
      out[rbase + row] = sui / (nu * nv);
    }
  }
}

extern "C" void kernel_launch(void* const* d_in, const int* in_sizes, int n_in,
                              void* d_out, int out_size, void* d_ws, size_t ws_size,
                              hipStream_t stream) {
  const int*   user_ids   = (const int*)d_in[0];
  const int*   item_ids   = (const int*)d_in[1];
  const float* user_table = (const float*)d_in[2];
  const float* item_table = (const float*)d_in[3];
  const float* uW1 = (const float*)d_in[4];
  const float* ub1 = (const float*)d_in[5];
  const float* uW2 = (const float*)d_in[6];
  const float* ub2 = (const float*)d_in[7];
  const float* iW1 = (const float*)d_in[8];
  const float* ib1 = (const float*)d_in[9];
  const float* iW2 = (const float*)d_in[10];
  const float* ib2 = (const float*)d_in[11];
  char* ws = (char*)d_ws;

  prep_kernel<<<130, 256, 0, stream>>>(uW1, ub1, uW2, ub2, iW1, ib1, iW2, ib2, ws);
  int nblk = out_size / 64;   // 8192 blocks x 64 rows
  TwoTowerModel_71708773974789_kernel<<<nblk, 256, 0, stream>>>(
      user_ids, item_ids, user_table, item_table, ws, (float*)d_out);
}